// Round 1
// baseline (1164.953 us; speedup 1.0000x reference)
//
#include <hip/hip_runtime.h>

// ---------------------------------------------------------------------------
// OptimEDM: denoised = softmax(-||x-y||^2 / 2s^2) @ y
//   x: (512, 3072) f32, sigma: (512,) f32, y: (50000, 3072) f32
// Plan:
//   K0 zero_out
//   K1 prep_x: x2[b], inv2s2[b], x -> bf16 hi/lo
//   K2 y2[n]
//   K3 QK:   S[b,n] = x.y via 3-term bf16 split MFMA; epilogue writes logits
//   K4 softmax rows -> P (bf16, normalized)
//   K5 PV:   out = P @ y  (split-K, fp32 atomics)
// ---------------------------------------------------------------------------

typedef __attribute__((ext_vector_type(4))) float f32x4;
typedef __attribute__((ext_vector_type(4))) unsigned short u16x4;
typedef __attribute__((ext_vector_type(8))) unsigned short u16x8;
typedef __attribute__((ext_vector_type(4))) unsigned int u32x4;
typedef __attribute__((ext_vector_type(8))) __bf16 bf16x8;

#define NREAL 50000
#define NP    50176   // 392 * 128, padded N
#define DD    3072
#define BB    512

__device__ __forceinline__ unsigned short f32_bf16_rne(float f) {
  unsigned int u = __float_as_uint(f);
  unsigned int r = 0x7FFFu + ((u >> 16) & 1u);
  return (unsigned short)((u + r) >> 16);
}
__device__ __forceinline__ float bf16_f32(unsigned short h) {
  return __uint_as_float(((unsigned int)h) << 16);
}

__global__ __launch_bounds__(256) void zero_kernel(f32x4* p) {
  p[(size_t)blockIdx.x * 256 + threadIdx.x] = (f32x4){0.f, 0.f, 0.f, 0.f};
}

__global__ __launch_bounds__(256) void prep_x_kernel(
    const float* __restrict__ x, const float* __restrict__ sigma,
    unsigned short* __restrict__ xhi, unsigned short* __restrict__ xlo,
    float* __restrict__ x2, float* __restrict__ inv2s2) {
  const int b = blockIdx.x, t = threadIdx.x;
  const f32x4* xr = (const f32x4*)(x + (size_t)b * DD);
  float ssq = 0.f;
#pragma unroll
  for (int i = 0; i < 3; ++i) {
    const int idx = i * 256 + t;
    f32x4 v = xr[idx];
    u16x4 h, l;
#pragma unroll
    for (int j = 0; j < 4; ++j) {
      float f = v[j];
      ssq += f * f;
      unsigned short hb = f32_bf16_rne(f);
      h[j] = hb;
      l[j] = f32_bf16_rne(f - bf16_f32(hb));
    }
    *(u16x4*)(xhi + (size_t)b * DD + idx * 4) = h;
    *(u16x4*)(xlo + (size_t)b * DD + idx * 4) = l;
  }
  __shared__ float red[4];
#pragma unroll
  for (int off = 32; off > 0; off >>= 1) ssq += __shfl_xor(ssq, off);
  if ((t & 63) == 0) red[t >> 6] = ssq;
  __syncthreads();
  if (t == 0) {
    x2[b] = red[0] + red[1] + red[2] + red[3];
    float s = sigma[b];
    inv2s2[b] = 1.0f / (2.0f * s * s);
  }
}

__global__ __launch_bounds__(256) void y2_kernel(const float* __restrict__ y,
                                                 float* __restrict__ y2) {
  const int n = blockIdx.x, t = threadIdx.x;
  const f32x4* yr = (const f32x4*)(y + (size_t)n * DD);
  float ssq = 0.f;
#pragma unroll
  for (int i = 0; i < 3; ++i) {
    f32x4 v = yr[i * 256 + t];
    ssq += v[0] * v[0] + v[1] * v[1] + v[2] * v[2] + v[3] * v[3];
  }
  __shared__ float red[4];
#pragma unroll
  for (int off = 32; off > 0; off >>= 1) ssq += __shfl_xor(ssq, off);
  if ((t & 63) == 0) red[t >> 6] = ssq;
  __syncthreads();
  if (t == 0) y2[n] = red[0] + red[1] + red[2] + red[3];
}

// ---------------------------------------------------------------------------
// QK: S[b,n] logits. Tile 128x128, BK=32, 4 waves (2x2), per-wave 64x64.
// 3 MFMAs per fragment pair: hi*hi + hi*lo + lo*hi  (bf16 double-word split)
// ---------------------------------------------------------------------------
__global__ __launch_bounds__(256) void qk_kernel(
    const float* __restrict__ y, const unsigned short* __restrict__ xhi,
    const unsigned short* __restrict__ xlo, const float* __restrict__ x2,
    const float* __restrict__ inv2s2, const float* __restrict__ y2,
    float* __restrict__ S) {
  // XCD swizzle: grid 1568 = 8*196; all 4 mt of one nt land on same XCD
  const int orig = blockIdx.x;
  const int virt = (orig & 7) * 196 + (orig >> 3);
  const int mt = virt & 3, nt = virt >> 2;
  const int m0 = mt * 128, n0 = nt * 128;
  const int t = threadIdx.x;
  const int lane = t & 63, w = t >> 6;
  const int wrow = w >> 1, wcol = w & 1;
  const int l15 = lane & 15, kb = (lane >> 4) * 8;

  __shared__ __align__(16) unsigned short Ah[128 * 40];
  __shared__ __align__(16) unsigned short Al[128 * 40];
  __shared__ __align__(16) unsigned short Bh[128 * 40];
  __shared__ __align__(16) unsigned short Bl[128 * 40];

  f32x4 acc[4][4] = {};
  u32x4 rah[2], ral[2];
  f32x4 rb[4];

  const int ar = t >> 2;         // 0..63  (A row base, +64)
  const int ac = (t & 3) * 8;    // 0,8,16,24
  const int br = t >> 3;         // 0..31  (B row base, +32*i)
  const int bc = (t & 7) * 4;    // 0..28

  auto LOADA = [&](int k0) {
#pragma unroll
    for (int i = 0; i < 2; ++i) {
      size_t off = (size_t)(m0 + ar + i * 64) * DD + k0 + ac;
      rah[i] = *(const u32x4*)(xhi + off);
      ral[i] = *(const u32x4*)(xlo + off);
    }
  };
  auto LOADB = [&](int k0) {
#pragma unroll
    for (int i = 0; i < 4; ++i) {
      int n = n0 + br + i * 32;
      if (n < NREAL)
        rb[i] = *(const f32x4*)(y + (size_t)n * DD + k0 + bc);
      else
        rb[i] = (f32x4){0.f, 0.f, 0.f, 0.f};
    }
  };
  auto STORE = [&]() {
#pragma unroll
    for (int i = 0; i < 2; ++i) {
      int row = ar + i * 64;
      *(u32x4*)(Ah + row * 40 + ac) = rah[i];
      *(u32x4*)(Al + row * 40 + ac) = ral[i];
    }
#pragma unroll
    for (int i = 0; i < 4; ++i) {
      int row = br + i * 32;
      u16x4 h, l;
#pragma unroll
      for (int j = 0; j < 4; ++j) {
        float f = rb[i][j];
        unsigned short hb = f32_bf16_rne(f);
        h[j] = hb;
        l[j] = f32_bf16_rne(f - bf16_f32(hb));
      }
      *(u16x4*)(Bh + row * 40 + bc) = h;
      *(u16x4*)(Bl + row * 40 + bc) = l;
    }
  };
  auto COMPUTE = [&]() {
    bf16x8 ah[4], al[4], bh[4], bl[4];
#pragma unroll
    for (int mi = 0; mi < 4; ++mi) {
      int row = wrow * 64 + mi * 16 + l15;
      ah[mi] = __builtin_bit_cast(bf16x8, *(const u16x8*)(Ah + row * 40 + kb));
      al[mi] = __builtin_bit_cast(bf16x8, *(const u16x8*)(Al + row * 40 + kb));
    }
#pragma unroll
    for (int ni = 0; ni < 4; ++ni) {
      int col = wcol * 64 + ni * 16 + l15;
      bh[ni] = __builtin_bit_cast(bf16x8, *(const u16x8*)(Bh + col * 40 + kb));
      bl[ni] = __builtin_bit_cast(bf16x8, *(const u16x8*)(Bl + col * 40 + kb));
    }
#pragma unroll
    for (int mi = 0; mi < 4; ++mi)
#pragma unroll
      for (int ni = 0; ni < 4; ++ni) {
        acc[mi][ni] = __builtin_amdgcn_mfma_f32_16x16x32_bf16(ah[mi], bh[ni], acc[mi][ni], 0, 0, 0);
        acc[mi][ni] = __builtin_amdgcn_mfma_f32_16x16x32_bf16(ah[mi], bl[ni], acc[mi][ni], 0, 0, 0);
        acc[mi][ni] = __builtin_amdgcn_mfma_f32_16x16x32_bf16(al[mi], bh[ni], acc[mi][ni], 0, 0, 0);
      }
  };

  LOADA(0);
  LOADB(0);
  for (int ks = 0; ks < 96; ++ks) {
    __syncthreads();
    STORE();
    __syncthreads();
    if (ks < 95) { LOADA((ks + 1) * 32); LOADB((ks + 1) * 32); }
    COMPUTE();
  }

  // epilogue: logits = -max(x2 + y2 - 2S, 0) / (2 sigma^2); pads -> -3e38
#pragma unroll
  for (int ni = 0; ni < 4; ++ni) {
    int col = n0 + wcol * 64 + ni * 16 + l15;
    float yy = (col < NREAL) ? y2[col] : 0.f;
#pragma unroll
    for (int mi = 0; mi < 4; ++mi) {
#pragma unroll
      for (int i = 0; i < 4; ++i) {
        int row = m0 + wrow * 64 + mi * 16 + ((lane >> 4) * 4) + i;
        float v;
        if (col < NREAL) {
          float d2 = fmaxf(x2[row] + yy - 2.0f * acc[mi][ni][i], 0.0f);
          v = -d2 * inv2s2[row];
        } else {
          v = -3.0e38f;
        }
        S[(size_t)row * NP + col] = v;
      }
    }
  }
}

// ---------------------------------------------------------------------------
// softmax per row: 3 sweeps (max, sum, write normalized bf16 P)
// ---------------------------------------------------------------------------
__global__ __launch_bounds__(256) void softmax_kernel(
    const float* __restrict__ S, unsigned short* __restrict__ P) {
  const int b = blockIdx.x, t = threadIdx.x;
  const f32x4* row = (const f32x4*)(S + (size_t)b * NP);
  __shared__ float red[4];

  float m = -3.4e38f;
#pragma unroll 4
  for (int i = 0; i < 49; ++i) {
    f32x4 v = row[i * 256 + t];
    m = fmaxf(m, fmaxf(fmaxf(v[0], v[1]), fmaxf(v[2], v[3])));
  }
#pragma unroll
  for (int off = 32; off > 0; off >>= 1) m = fmaxf(m, __shfl_xor(m, off));
  if ((t & 63) == 0) red[t >> 6] = m;
  __syncthreads();
  m = fmaxf(fmaxf(red[0], red[1]), fmaxf(red[2], red[3]));
  __syncthreads();

  float sum = 0.f;
#pragma unroll 4
  for (int i = 0; i < 49; ++i) {
    f32x4 v = row[i * 256 + t];
    sum += __expf(v[0] - m) + __expf(v[1] - m) + __expf(v[2] - m) + __expf(v[3] - m);
  }
#pragma unroll
  for (int off = 32; off > 0; off >>= 1) sum += __shfl_xor(sum, off);
  if ((t & 63) == 0) red[t >> 6] = sum;
  __syncthreads();
  const float inv = 1.0f / (red[0] + red[1] + red[2] + red[3]);

  unsigned short* pr = P + (size_t)b * NP;
#pragma unroll 4
  for (int i = 0; i < 49; ++i) {
    const int e = i * 256 + t;
    f32x4 v = row[e];
    u16x4 o;
    o[0] = f32_bf16_rne(__expf(v[0] - m) * inv);
    o[1] = f32_bf16_rne(__expf(v[1] - m) * inv);
    o[2] = f32_bf16_rne(__expf(v[2] - m) * inv);
    o[3] = f32_bf16_rne(__expf(v[3] - m) * inv);
    *(u16x4*)(pr + (size_t)e * 4) = o;
  }
}

// ---------------------------------------------------------------------------
// PV: out = P @ y. Tile 128(b) x 128(d), BK=32(n), split-K=8, atomics.
// y staged transposed (LDS [d][n]) with fp32->bf16 convert.
// ---------------------------------------------------------------------------
__global__ __launch_bounds__(256) void pv_kernel(const float* __restrict__ y,
                                                 const unsigned short* __restrict__ P,
                                                 float* __restrict__ out) {
  // swizzle: grid 768 = 8*96; 4 mt sharing (dt,sp) stay on one XCD
  const int orig = blockIdx.x;
  const int virt = (orig & 7) * 96 + (orig >> 3);
  const int mt = virt & 3;
  const int dt = (virt >> 2) % 24;
  const int sp = virt / 96;
  const int m0 = mt * 128, d0 = dt * 128;
  const int kbeg = sp * 6272;  // 50176/8, 196 K-steps of 32

  const int t = threadIdx.x, lane = t & 63, w = t >> 6;
  const int wrow = w >> 1, wcol = w & 1;
  const int l15 = lane & 15, kb = (lane >> 4) * 8;

  __shared__ __align__(16) unsigned short Ap[128 * 40];
  __shared__ __align__(16) unsigned short Bt[128 * 40];

  f32x4 acc[4][4] = {};
  u32x4 ra[2];
  f32x4 rb[4];

  const int ar = t >> 2, ac = (t & 3) * 8;
  const int dcol = (t & 31) * 4;   // 0..124
  const int nr = (t >> 5) * 4;     // 0..28

  auto LOADA = [&](int k0) {
#pragma unroll
    for (int i = 0; i < 2; ++i)
      ra[i] = *(const u32x4*)(P + (size_t)(m0 + ar + i * 64) * NP + k0 + ac);
  };
  auto LOADB = [&](int k0) {
#pragma unroll
    for (int i = 0; i < 4; ++i) {
      int n = k0 + nr + i;
      if (n < NREAL)
        rb[i] = *(const f32x4*)(y + (size_t)n * DD + d0 + dcol);
      else
        rb[i] = (f32x4){0.f, 0.f, 0.f, 0.f};
    }
  };
  auto STORE = [&]() {
#pragma unroll
    for (int i = 0; i < 2; ++i)
      *(u32x4*)(Ap + (ar + i * 64) * 40 + ac) = ra[i];
#pragma unroll
    for (int j = 0; j < 4; ++j) {
      u16x4 h;
#pragma unroll
      for (int i = 0; i < 4; ++i) h[i] = f32_bf16_rne(rb[i][j]);
      *(u16x4*)(Bt + (dcol + j) * 40 + nr) = h;
    }
  };
  auto COMPUTE = [&]() {
    bf16x8 a[4], bv[4];
#pragma unroll
    for (int mi = 0; mi < 4; ++mi)
      a[mi] = __builtin_bit_cast(bf16x8, *(const u16x8*)(Ap + (wrow * 64 + mi * 16 + l15) * 40 + kb));
#pragma unroll
    for (int ni = 0; ni < 4; ++ni)
      bv[ni] = __builtin_bit_cast(bf16x8, *(const u16x8*)(Bt + (wcol * 64 + ni * 16 + l15) * 40 + kb));
#pragma unroll
    for (int mi = 0; mi < 4; ++mi)
#pragma unroll
      for (int ni = 0; ni < 4; ++ni)
        acc[mi][ni] = __builtin_amdgcn_mfma_f32_16x16x32_bf16(a[mi], bv[ni], acc[mi][ni], 0, 0, 0);
  };

  LOADA(kbeg);
  LOADB(kbeg);
  for (int ks = 0; ks < 196; ++ks) {
    __syncthreads();
    STORE();
    __syncthreads();
    if (ks < 195) { LOADA(kbeg + (ks + 1) * 32); LOADB(kbeg + (ks + 1) * 32); }
    COMPUTE();
  }

#pragma unroll
  for (int mi = 0; mi < 4; ++mi)
#pragma unroll
    for (int ni = 0; ni < 4; ++ni)
#pragma unroll
      for (int i = 0; i < 4; ++i) {
        int row = m0 + wrow * 64 + mi * 16 + ((lane >> 4) * 4) + i;
        int col = d0 + wcol * 64 + ni * 16 + l15;
        unsafeAtomicAdd(out + (size_t)row * DD + col, acc[mi][ni][i]);
      }
}

// ---------------------------------------------------------------------------
extern "C" void kernel_launch(void* const* d_in, const int* in_sizes, int n_in,
                              void* d_out, int out_size, void* d_ws, size_t ws_size,
                              hipStream_t stream) {
  const float* x = (const float*)d_in[0];
  const float* sigma = (const float*)d_in[1];
  const float* y = (const float*)d_in[2];
  float* out = (float*)d_out;

  char* ws = (char*)d_ws;
  size_t off = 0;
  float* S = (float*)(ws + off);            off += (size_t)BB * NP * 4;   // 102.8 MB
  unsigned short* P = (unsigned short*)(ws + off); off += (size_t)BB * NP * 2; // 51.4 MB
  unsigned short* xhi = (unsigned short*)(ws + off); off += (size_t)BB * DD * 2;
  unsigned short* xlo = (unsigned short*)(ws + off); off += (size_t)BB * DD * 2;
  float* y2 = (float*)(ws + off);           off += (size_t)NP * 4;
  float* x2 = (float*)(ws + off);           off += 512 * 4;
  float* inv2s2 = (float*)(ws + off);       off += 512 * 4;
  if (ws_size < off) return;  // workspace too small: fail loudly

  zero_kernel<<<dim3(1536), dim3(256), 0, stream>>>((f32x4*)out);
  prep_x_kernel<<<dim3(512), dim3(256), 0, stream>>>(x, sigma, xhi, xlo, x2, inv2s2);
  y2_kernel<<<dim3(NREAL), dim3(256), 0, stream>>>(y, y2);
  qk_kernel<<<dim3(1568), dim3(256), 0, stream>>>(y, xhi, xlo, x2, inv2s2, y2, S);
  softmax_kernel<<<dim3(512), dim3(256), 0, stream>>>(S, P);
  pv_kernel<<<dim3(768), dim3(256), 0, stream>>>(y, P, out);
}

// Round 2
// 1125.210 us; speedup vs baseline: 1.0353x; 1.0353x over previous
//
#include <hip/hip_runtime.h>

// ---------------------------------------------------------------------------
// OptimEDM: denoised = softmax(-||x-y||^2 / 2s^2) @ y
//   x: (512, 3072) f32, sigma: (512,) f32, y: (50000, 3072) f32
// Round 2: pre-convert y to bf16 hi/lo (prep_y, fused with y2);
//          QK/PV stage via global_load_lds with both-sides XOR chunk swizzle.
//          Fallback to round-1 path if workspace too small.
// ---------------------------------------------------------------------------

typedef __attribute__((ext_vector_type(4))) float f32x4;
typedef __attribute__((ext_vector_type(4))) unsigned short u16x4;
typedef __attribute__((ext_vector_type(8))) unsigned short u16x8;
typedef __attribute__((ext_vector_type(4))) unsigned int u32x4;
typedef __attribute__((ext_vector_type(8))) __bf16 bf16x8;

#define NREAL 50000
#define NP    50176   // 392 * 128
#define DD    3072
#define BB    512

__device__ __forceinline__ unsigned short f32_bf16_rne(float f) {
  unsigned int u = __float_as_uint(f);
  unsigned int r = 0x7FFFu + ((u >> 16) & 1u);
  return (unsigned short)((u + r) >> 16);
}
__device__ __forceinline__ float bf16_f32(unsigned short h) {
  return __uint_as_float(((unsigned int)h) << 16);
}
__device__ __forceinline__ void gload16(const unsigned short* g, unsigned short* l) {
  __builtin_amdgcn_global_load_lds(
      (const __attribute__((address_space(1))) void*)g,
      (__attribute__((address_space(3))) void*)l, 16, 0, 0);
}

__global__ __launch_bounds__(256) void zero_kernel(f32x4* p) {
  p[(size_t)blockIdx.x * 256 + threadIdx.x] = (f32x4){0.f, 0.f, 0.f, 0.f};
}

__global__ __launch_bounds__(256) void prep_x_kernel(
    const float* __restrict__ x, const float* __restrict__ sigma,
    unsigned short* __restrict__ xhi, unsigned short* __restrict__ xlo,
    float* __restrict__ x2, float* __restrict__ inv2s2) {
  const int b = blockIdx.x, t = threadIdx.x;
  const f32x4* xr = (const f32x4*)(x + (size_t)b * DD);
  float ssq = 0.f;
#pragma unroll
  for (int i = 0; i < 3; ++i) {
    const int idx = i * 256 + t;
    f32x4 v = xr[idx];
    u16x4 h, l;
#pragma unroll
    for (int j = 0; j < 4; ++j) {
      float f = v[j];
      ssq += f * f;
      unsigned short hb = f32_bf16_rne(f);
      h[j] = hb;
      l[j] = f32_bf16_rne(f - bf16_f32(hb));
    }
    *(u16x4*)(xhi + (size_t)b * DD + idx * 4) = h;
    *(u16x4*)(xlo + (size_t)b * DD + idx * 4) = l;
  }
  __shared__ float red[4];
#pragma unroll
  for (int off = 32; off > 0; off >>= 1) ssq += __shfl_xor(ssq, off);
  if ((t & 63) == 0) red[t >> 6] = ssq;
  __syncthreads();
  if (t == 0) {
    x2[b] = red[0] + red[1] + red[2] + red[3];
    float s = sigma[b];
    inv2s2[b] = 1.0f / (2.0f * s * s);
  }
}

// prep_y: y -> (yhi, ylo) bf16 split + y2, pads (n>=NREAL) zeroed.
__global__ __launch_bounds__(256) void prep_y_kernel(
    const float* __restrict__ y, unsigned short* __restrict__ yhi,
    unsigned short* __restrict__ ylo, float* __restrict__ y2) {
  const int n = blockIdx.x, t = threadIdx.x;
  if (n >= NREAL) {
    u16x4 z = {0, 0, 0, 0};
#pragma unroll
    for (int i = 0; i < 3; ++i) {
      *(u16x4*)(yhi + (size_t)n * DD + (i * 256 + t) * 4) = z;
      *(u16x4*)(ylo + (size_t)n * DD + (i * 256 + t) * 4) = z;
    }
    if (t == 0) y2[n] = 0.f;
    return;
  }
  const f32x4* yr = (const f32x4*)(y + (size_t)n * DD);
  float ssq = 0.f;
#pragma unroll
  for (int i = 0; i < 3; ++i) {
    const int idx = i * 256 + t;
    f32x4 v = yr[idx];
    u16x4 h, l;
#pragma unroll
    for (int j = 0; j < 4; ++j) {
      float f = v[j];
      ssq += f * f;
      unsigned short hb = f32_bf16_rne(f);
      h[j] = hb;
      l[j] = f32_bf16_rne(f - bf16_f32(hb));
    }
    *(u16x4*)(yhi + (size_t)n * DD + idx * 4) = h;
    *(u16x4*)(ylo + (size_t)n * DD + idx * 4) = l;
  }
  __shared__ float red[4];
#pragma unroll
  for (int off = 32; off > 0; off >>= 1) ssq += __shfl_xor(ssq, off);
  if ((t & 63) == 0) red[t >> 6] = ssq;
  __syncthreads();
  if (t == 0) y2[n] = red[0] + red[1] + red[2] + red[3];
}

// ---------------------------------------------------------------------------
// QK main: 128x128 tile, BK=32, global_load_lds staging, XOR chunk swizzle.
// LDS layout: [128 rows][4 chunks of 8 bf16]; stored chunk c holds global
// chunk c ^ ((row>>1)&3). Source pre-swizzled, read applies same XOR.
// ---------------------------------------------------------------------------
__global__ __launch_bounds__(256) void qk_kernel(
    const unsigned short* __restrict__ yhi, const unsigned short* __restrict__ ylo,
    const unsigned short* __restrict__ xhi, const unsigned short* __restrict__ xlo,
    const float* __restrict__ x2, const float* __restrict__ inv2s2,
    const float* __restrict__ y2, float* __restrict__ S) {
  const int orig = blockIdx.x;
  const int virt = (orig & 7) * 196 + (orig >> 3);  // 1568 = 8*196, bijective
  const int mt = virt & 3, nt = virt >> 2;
  const int m0 = mt * 128, n0 = nt * 128;
  const int t = threadIdx.x;
  const int lane = t & 63, w = t >> 6;
  const int wrow = w >> 1, wcol = w & 1;
  const int l15 = lane & 15, kb = (lane >> 4) * 8;

  __shared__ __align__(16) unsigned short Ah[4096];
  __shared__ __align__(16) unsigned short Al[4096];
  __shared__ __align__(16) unsigned short Bh[4096];
  __shared__ __align__(16) unsigned short Bl[4096];

  f32x4 acc[4][4] = {};

  // staging: thread t -> row srow(+64), source chunk swizzled
  const int srow = t >> 2;
  const int schunk = (((t & 3) ^ ((t >> 3) & 3))) * 8;  // global col elems
  const int sdst = t * 8;                                // LDS elem off (r=0)
  // fragment read: swizzled chunk, per-thread constant
  const int cs8 = (((lane >> 4) ^ ((l15 >> 1) & 3))) * 8;

  auto STAGE = [&](int k0) {
#pragma unroll
    for (int r = 0; r < 2; ++r) {
      const int row = srow + r * 64;
      const size_t ga = (size_t)(m0 + row) * DD + k0 + schunk;
      const size_t gb = (size_t)(n0 + row) * DD + k0 + schunk;
      const int ld = sdst + r * 2048;
      gload16(xhi + ga, Ah + ld);
      gload16(xlo + ga, Al + ld);
      gload16(yhi + gb, Bh + ld);
      gload16(ylo + gb, Bl + ld);
    }
  };
  auto COMPUTE = [&]() {
    bf16x8 ah[4], al[4], bh[4], bl[4];
#pragma unroll
    for (int mi = 0; mi < 4; ++mi) {
      const int off = (wrow * 64 + mi * 16 + l15) * 32 + cs8;
      ah[mi] = __builtin_bit_cast(bf16x8, *(const u16x8*)(Ah + off));
      al[mi] = __builtin_bit_cast(bf16x8, *(const u16x8*)(Al + off));
    }
#pragma unroll
    for (int ni = 0; ni < 4; ++ni) {
      const int off = (wcol * 64 + ni * 16 + l15) * 32 + cs8;
      bh[ni] = __builtin_bit_cast(bf16x8, *(const u16x8*)(Bh + off));
      bl[ni] = __builtin_bit_cast(bf16x8, *(const u16x8*)(Bl + off));
    }
#pragma unroll
    for (int mi = 0; mi < 4; ++mi)
#pragma unroll
      for (int ni = 0; ni < 4; ++ni) {
        acc[mi][ni] = __builtin_amdgcn_mfma_f32_16x16x32_bf16(ah[mi], bh[ni], acc[mi][ni], 0, 0, 0);
        acc[mi][ni] = __builtin_amdgcn_mfma_f32_16x16x32_bf16(ah[mi], bl[ni], acc[mi][ni], 0, 0, 0);
        acc[mi][ni] = __builtin_amdgcn_mfma_f32_16x16x32_bf16(al[mi], bh[ni], acc[mi][ni], 0, 0, 0);
      }
  };

  STAGE(0);
  for (int ks = 0; ks < 96; ++ks) {
    __syncthreads();   // drains vmcnt: staged tile visible
    COMPUTE();
    __syncthreads();   // all reads done before overwrite
    if (ks < 95) STAGE((ks + 1) * 32);
  }

#pragma unroll
  for (int ni = 0; ni < 4; ++ni) {
    int col = n0 + wcol * 64 + ni * 16 + l15;
    float yy = (col < NREAL) ? y2[col] : 0.f;
#pragma unroll
    for (int mi = 0; mi < 4; ++mi) {
#pragma unroll
      for (int i = 0; i < 4; ++i) {
        int row = m0 + wrow * 64 + mi * 16 + ((lane >> 4) * 4) + i;
        float v;
        if (col < NREAL) {
          float d2 = fmaxf(x2[row] + yy - 2.0f * acc[mi][ni][i], 0.0f);
          v = -d2 * inv2s2[row];
        } else {
          v = -3.0e38f;
        }
        S[(size_t)row * NP + col] = v;
      }
    }
  }
}

// ---------------------------------------------------------------------------
// softmax per row: 3 sweeps (max, sum, write normalized bf16 P)
// ---------------------------------------------------------------------------
__global__ __launch_bounds__(256) void softmax_kernel(
    const float* __restrict__ S, unsigned short* __restrict__ P) {
  const int b = blockIdx.x, t = threadIdx.x;
  const f32x4* row = (const f32x4*)(S + (size_t)b * NP);
  __shared__ float red[4];

  float m = -3.4e38f;
#pragma unroll 4
  for (int i = 0; i < 49; ++i) {
    f32x4 v = row[i * 256 + t];
    m = fmaxf(m, fmaxf(fmaxf(v[0], v[1]), fmaxf(v[2], v[3])));
  }
#pragma unroll
  for (int off = 32; off > 0; off >>= 1) m = fmaxf(m, __shfl_xor(m, off));
  if ((t & 63) == 0) red[t >> 6] = m;
  __syncthreads();
  m = fmaxf(fmaxf(red[0], red[1]), fmaxf(red[2], red[3]));
  __syncthreads();

  float sum = 0.f;
#pragma unroll 4
  for (int i = 0; i < 49; ++i) {
    f32x4 v = row[i * 256 + t];
    sum += __expf(v[0] - m) + __expf(v[1] - m) + __expf(v[2] - m) + __expf(v[3] - m);
  }
#pragma unroll
  for (int off = 32; off > 0; off >>= 1) sum += __shfl_xor(sum, off);
  if ((t & 63) == 0) red[t >> 6] = sum;
  __syncthreads();
  const float inv = 1.0f / (red[0] + red[1] + red[2] + red[3]);

  unsigned short* pr = P + (size_t)b * NP;
#pragma unroll 4
  for (int i = 0; i < 49; ++i) {
    const int e = i * 256 + t;
    f32x4 v = row[e];
    u16x4 o;
    o[0] = f32_bf16_rne(__expf(v[0] - m) * inv);
    o[1] = f32_bf16_rne(__expf(v[1] - m) * inv);
    o[2] = f32_bf16_rne(__expf(v[2] - m) * inv);
    o[3] = f32_bf16_rne(__expf(v[3] - m) * inv);
    *(u16x4*)(pr + (size_t)e * 4) = o;
  }
}

// ---------------------------------------------------------------------------
// PV main: out = P @ yhi. A via gload_lds (dbuf, swizzled), B = bf16 y rows
// transposed through regs into padded Bt. split-K=8 + fp32 atomics.
// ---------------------------------------------------------------------------
__global__ __launch_bounds__(256) void pv_kernel(
    const unsigned short* __restrict__ yhi, const unsigned short* __restrict__ P,
    float* __restrict__ out) {
  const int orig = blockIdx.x;
  const int virt = (orig & 7) * 96 + (orig >> 3);  // 768 = 8*96, bijective
  const int mt = virt & 3;
  const int dt = (virt >> 2) % 24;
  const int sp = virt / 96;
  const int m0 = mt * 128, d0 = dt * 128;
  const int kbeg = sp * 6272;

  const int t = threadIdx.x, lane = t & 63, w = t >> 6;
  const int wrow = w >> 1, wcol = w & 1;
  const int l15 = lane & 15, kb = (lane >> 4) * 8;

  __shared__ __align__(16) unsigned short Ap[2][4096];
  __shared__ __align__(16) unsigned short Bt[128 * 40];

  f32x4 acc[4][4] = {};
  u16x4 rbh[4];

  const int srow = t >> 2;
  const int schunk = (((t & 3) ^ ((t >> 3) & 3))) * 8;
  const int sdst = t * 8;
  const int cs8 = (((lane >> 4) ^ ((l15 >> 1) & 3))) * 8;
  const int dcol = (t & 31) * 4;
  const int nr = (t >> 5) * 4;

  auto STAGEA = [&](int k0, int b) {
#pragma unroll
    for (int r = 0; r < 2; ++r)
      gload16(P + (size_t)(m0 + srow + r * 64) * NP + k0 + schunk,
              Ap[b] + sdst + r * 2048);
  };
  auto LOADB = [&](int k0) {
#pragma unroll
    for (int i = 0; i < 4; ++i)
      rbh[i] = *(const u16x4*)(yhi + (size_t)(k0 + nr + i) * DD + d0 + dcol);
  };
  auto STOREB = [&]() {
#pragma unroll
    for (int j = 0; j < 4; ++j) {
      u16x4 h;
#pragma unroll
      for (int i = 0; i < 4; ++i) h[i] = rbh[i][j];
      *(u16x4*)(Bt + (dcol + j) * 40 + nr) = h;
    }
  };
  auto COMPUTE = [&](int b) {
    bf16x8 a[4], bv[4];
#pragma unroll
    for (int mi = 0; mi < 4; ++mi)
      a[mi] = __builtin_bit_cast(bf16x8, *(const u16x8*)(Ap[b] + (wrow * 64 + mi * 16 + l15) * 32 + cs8));
#pragma unroll
    for (int ni = 0; ni < 4; ++ni)
      bv[ni] = __builtin_bit_cast(bf16x8, *(const u16x8*)(Bt + (wcol * 64 + ni * 16 + l15) * 40 + kb));
#pragma unroll
    for (int mi = 0; mi < 4; ++mi)
#pragma unroll
      for (int ni = 0; ni < 4; ++ni)
        acc[mi][ni] = __builtin_amdgcn_mfma_f32_16x16x32_bf16(a[mi], bv[ni], acc[mi][ni], 0, 0, 0);
  };

  STAGEA(kbeg, 0);
  LOADB(kbeg);
  int bf = 0;
  for (int ks = 0; ks < 196; ++ks) {
    __syncthreads();             // drain A gloads(bf) + prev compute done
    STOREB();
    if (ks < 195) { STAGEA(kbeg + (ks + 1) * 32, bf ^ 1); LOADB(kbeg + (ks + 1) * 32); }
    __syncthreads();             // Bt visible
    COMPUTE(bf);
    bf ^= 1;
  }

#pragma unroll
  for (int mi = 0; mi < 4; ++mi)
#pragma unroll
    for (int ni = 0; ni < 4; ++ni)
#pragma unroll
      for (int i = 0; i < 4; ++i) {
        int row = m0 + wrow * 64 + mi * 16 + ((lane >> 4) * 4) + i;
        int col = d0 + wcol * 64 + ni * 16 + l15;
        unsafeAtomicAdd(out + (size_t)row * DD + col, acc[mi][ni][i]);
      }
}

// ===========================================================================
// Fallback path (round-1 kernels) — used only if ws_size is too small for
// the pre-converted-y plan. Known-good.
// ===========================================================================
__global__ __launch_bounds__(256) void y2_kernel(const float* __restrict__ y,
                                                 float* __restrict__ y2) {
  const int n = blockIdx.x, t = threadIdx.x;
  const f32x4* yr = (const f32x4*)(y + (size_t)n * DD);
  float ssq = 0.f;
#pragma unroll
  for (int i = 0; i < 3; ++i) {
    f32x4 v = yr[i * 256 + t];
    ssq += v[0] * v[0] + v[1] * v[1] + v[2] * v[2] + v[3] * v[3];
  }
  __shared__ float red[4];
#pragma unroll
  for (int off = 32; off > 0; off >>= 1) ssq += __shfl_xor(ssq, off);
  if ((t & 63) == 0) red[t >> 6] = ssq;
  __syncthreads();
  if (t == 0) y2[n] = red[0] + red[1] + red[2] + red[3];
}

__global__ __launch_bounds__(256) void qk_fb_kernel(
    const float* __restrict__ y, const unsigned short* __restrict__ xhi,
    const unsigned short* __restrict__ xlo, const float* __restrict__ x2,
    const float* __restrict__ inv2s2, const float* __restrict__ y2,
    float* __restrict__ S) {
  const int orig = blockIdx.x;
  const int virt = (orig & 7) * 196 + (orig >> 3);
  const int mt = virt & 3, nt = virt >> 2;
  const int m0 = mt * 128, n0 = nt * 128;
  const int t = threadIdx.x;
  const int lane = t & 63, w = t >> 6;
  const int wrow = w >> 1, wcol = w & 1;
  const int l15 = lane & 15, kb = (lane >> 4) * 8;

  __shared__ __align__(16) unsigned short Ah[128 * 40];
  __shared__ __align__(16) unsigned short Al[128 * 40];
  __shared__ __align__(16) unsigned short Bh[128 * 40];
  __shared__ __align__(16) unsigned short Bl[128 * 40];

  f32x4 acc[4][4] = {};
  u32x4 rah[2], ral[2];
  f32x4 rb[4];

  const int ar = t >> 2, ac = (t & 3) * 8;
  const int br = t >> 3, bc = (t & 7) * 4;

  auto LOADA = [&](int k0) {
#pragma unroll
    for (int i = 0; i < 2; ++i) {
      size_t off = (size_t)(m0 + ar + i * 64) * DD + k0 + ac;
      rah[i] = *(const u32x4*)(xhi + off);
      ral[i] = *(const u32x4*)(xlo + off);
    }
  };
  auto LOADB = [&](int k0) {
#pragma unroll
    for (int i = 0; i < 4; ++i) {
      int n = n0 + br + i * 32;
      if (n < NREAL)
        rb[i] = *(const f32x4*)(y + (size_t)n * DD + k0 + bc);
      else
        rb[i] = (f32x4){0.f, 0.f, 0.f, 0.f};
    }
  };
  auto STORE = [&]() {
#pragma unroll
    for (int i = 0; i < 2; ++i) {
      int row = ar + i * 64;
      *(u32x4*)(Ah + row * 40 + ac) = rah[i];
      *(u32x4*)(Al + row * 40 + ac) = ral[i];
    }
#pragma unroll
    for (int i = 0; i < 4; ++i) {
      int row = br + i * 32;
      u16x4 h, l;
#pragma unroll
      for (int j = 0; j < 4; ++j) {
        float f = rb[i][j];
        unsigned short hb = f32_bf16_rne(f);
        h[j] = hb;
        l[j] = f32_bf16_rne(f - bf16_f32(hb));
      }
      *(u16x4*)(Bh + row * 40 + bc) = h;
      *(u16x4*)(Bl + row * 40 + bc) = l;
    }
  };
  auto COMPUTE = [&]() {
    bf16x8 ah[4], al[4], bh[4], bl[4];
#pragma unroll
    for (int mi = 0; mi < 4; ++mi) {
      int row = wrow * 64 + mi * 16 + l15;
      ah[mi] = __builtin_bit_cast(bf16x8, *(const u16x8*)(Ah + row * 40 + kb));
      al[mi] = __builtin_bit_cast(bf16x8, *(const u16x8*)(Al + row * 40 + kb));
    }
#pragma unroll
    for (int ni = 0; ni < 4; ++ni) {
      int col = wcol * 64 + ni * 16 + l15;
      bh[ni] = __builtin_bit_cast(bf16x8, *(const u16x8*)(Bh + col * 40 + kb));
      bl[ni] = __builtin_bit_cast(bf16x8, *(const u16x8*)(Bl + col * 40 + kb));
    }
#pragma unroll
    for (int mi = 0; mi < 4; ++mi)
#pragma unroll
      for (int ni = 0; ni < 4; ++ni) {
        acc[mi][ni] = __builtin_amdgcn_mfma_f32_16x16x32_bf16(ah[mi], bh[ni], acc[mi][ni], 0, 0, 0);
        acc[mi][ni] = __builtin_amdgcn_mfma_f32_16x16x32_bf16(ah[mi], bl[ni], acc[mi][ni], 0, 0, 0);
        acc[mi][ni] = __builtin_amdgcn_mfma_f32_16x16x32_bf16(al[mi], bh[ni], acc[mi][ni], 0, 0, 0);
      }
  };

  LOADA(0);
  LOADB(0);
  for (int ks = 0; ks < 96; ++ks) {
    __syncthreads();
    STORE();
    __syncthreads();
    if (ks < 95) { LOADA((ks + 1) * 32); LOADB((ks + 1) * 32); }
    COMPUTE();
  }

#pragma unroll
  for (int ni = 0; ni < 4; ++ni) {
    int col = n0 + wcol * 64 + ni * 16 + l15;
    float yy = (col < NREAL) ? y2[col] : 0.f;
#pragma unroll
    for (int mi = 0; mi < 4; ++mi) {
#pragma unroll
      for (int i = 0; i < 4; ++i) {
        int row = m0 + wrow * 64 + mi * 16 + ((lane >> 4) * 4) + i;
        float v;
        if (col < NREAL) {
          float d2 = fmaxf(x2[row] + yy - 2.0f * acc[mi][ni][i], 0.0f);
          v = -d2 * inv2s2[row];
        } else {
          v = -3.0e38f;
        }
        S[(size_t)row * NP + col] = v;
      }
    }
  }
}

__global__ __launch_bounds__(256) void pv_fb_kernel(const float* __restrict__ y,
                                                    const unsigned short* __restrict__ P,
                                                    float* __restrict__ out) {
  const int orig = blockIdx.x;
  const int virt = (orig & 7) * 96 + (orig >> 3);
  const int mt = virt & 3;
  const int dt = (virt >> 2) % 24;
  const int sp = virt / 96;
  const int m0 = mt * 128, d0 = dt * 128;
  const int kbeg = sp * 6272;

  const int t = threadIdx.x, lane = t & 63, w = t >> 6;
  const int wrow = w >> 1, wcol = w & 1;
  const int l15 = lane & 15, kb = (lane >> 4) * 8;

  __shared__ __align__(16) unsigned short Ap[128 * 40];
  __shared__ __align__(16) unsigned short Bt[128 * 40];

  f32x4 acc[4][4] = {};
  u32x4 ra[2];
  f32x4 rb[4];

  const int ar = t >> 2, ac = (t & 3) * 8;
  const int dcol = (t & 31) * 4;
  const int nr = (t >> 5) * 4;

  auto LOADA = [&](int k0) {
#pragma unroll
    for (int i = 0; i < 2; ++i)
      ra[i] = *(const u32x4*)(P + (size_t)(m0 + ar + i * 64) * NP + k0 + ac);
  };
  auto LOADB = [&](int k0) {
#pragma unroll
    for (int i = 0; i < 4; ++i) {
      int n = k0 + nr + i;
      if (n < NREAL)
        rb[i] = *(const f32x4*)(y + (size_t)n * DD + d0 + dcol);
      else
        rb[i] = (f32x4){0.f, 0.f, 0.f, 0.f};
    }
  };
  auto STORE = [&]() {
#pragma unroll
    for (int i = 0; i < 2; ++i)
      *(u32x4*)(Ap + (ar + i * 64) * 40 + ac) = ra[i];
#pragma unroll
    for (int j = 0; j < 4; ++j) {
      u16x4 h;
#pragma unroll
      for (int i = 0; i < 4; ++i) h[i] = f32_bf16_rne(rb[i][j]);
      *(u16x4*)(Bt + (dcol + j) * 40 + nr) = h;
    }
  };
  auto COMPUTE = [&]() {
    bf16x8 a[4], bv[4];
#pragma unroll
    for (int mi = 0; mi < 4; ++mi)
      a[mi] = __builtin_bit_cast(bf16x8, *(const u16x8*)(Ap + (wrow * 64 + mi * 16 + l15) * 40 + kb));
#pragma unroll
    for (int ni = 0; ni < 4; ++ni)
      bv[ni] = __builtin_bit_cast(bf16x8, *(const u16x8*)(Bt + (wcol * 64 + ni * 16 + l15) * 40 + kb));
#pragma unroll
    for (int mi = 0; mi < 4; ++mi)
#pragma unroll
      for (int ni = 0; ni < 4; ++ni)
        acc[mi][ni] = __builtin_amdgcn_mfma_f32_16x16x32_bf16(a[mi], bv[ni], acc[mi][ni], 0, 0, 0);
  };

  LOADA(kbeg);
  LOADB(kbeg);
  for (int ks = 0; ks < 196; ++ks) {
    __syncthreads();
    STORE();
    __syncthreads();
    if (ks < 195) { LOADA(kbeg + (ks + 1) * 32); LOADB(kbeg + (ks + 1) * 32); }
    COMPUTE();
  }

#pragma unroll
  for (int mi = 0; mi < 4; ++mi)
#pragma unroll
    for (int ni = 0; ni < 4; ++ni)
#pragma unroll
      for (int i = 0; i < 4; ++i) {
        int row = m0 + wrow * 64 + mi * 16 + ((lane >> 4) * 4) + i;
        int col = d0 + wcol * 64 + ni * 16 + l15;
        unsafeAtomicAdd(out + (size_t)row * DD + col, acc[mi][ni][i]);
      }
}

// ---------------------------------------------------------------------------
extern "C" void kernel_launch(void* const* d_in, const int* in_sizes, int n_in,
                              void* d_out, int out_size, void* d_ws, size_t ws_size,
                              hipStream_t stream) {
  const float* x = (const float*)d_in[0];
  const float* sigma = (const float*)d_in[1];
  const float* y = (const float*)d_in[2];
  float* out = (float*)d_out;
  char* ws = (char*)d_ws;

  // main layout
  size_t off = 0;
  float* S = (float*)(ws + off);                      off += (size_t)BB * NP * 4;
  unsigned short* yhi = (unsigned short*)(ws + off);  off += (size_t)NP * DD * 2;
  unsigned short* ylo = (unsigned short*)(ws + off);  off += (size_t)NP * DD * 2;
  unsigned short* P = ylo;  // ylo dead after QK; softmax writes P here
  unsigned short* xhi = (unsigned short*)(ws + off);  off += (size_t)BB * DD * 2;
  unsigned short* xlo = (unsigned short*)(ws + off);  off += (size_t)BB * DD * 2;
  float* y2 = (float*)(ws + off);                     off += (size_t)NP * 4;
  float* x2 = (float*)(ws + off);                     off += 512 * 4;
  float* inv2s2 = (float*)(ws + off);                 off += 512 * 4;

  if (ws_size >= off) {
    zero_kernel<<<dim3(1536), dim3(256), 0, stream>>>((f32x4*)out);
    prep_x_kernel<<<dim3(512), dim3(256), 0, stream>>>(x, sigma, xhi, xlo, x2, inv2s2);
    prep_y_kernel<<<dim3(NP), dim3(256), 0, stream>>>(y, yhi, ylo, y2);
    qk_kernel<<<dim3(1568), dim3(256), 0, stream>>>(yhi, ylo, xhi, xlo, x2, inv2s2, y2, S);
    softmax_kernel<<<dim3(512), dim3(256), 0, stream>>>(S, P);
    pv_kernel<<<dim3(768), dim3(256), 0, stream>>>(yhi, P, out);
    return;
  }

  // fallback layout (round-1)
  off = 0;
  float* Sf = (float*)(ws + off);                      off += (size_t)BB * NP * 4;
  unsigned short* Pf = (unsigned short*)(ws + off);    off += (size_t)BB * NP * 2;
  unsigned short* xhif = (unsigned short*)(ws + off);  off += (size_t)BB * DD * 2;
  unsigned short* xlof = (unsigned short*)(ws + off);  off += (size_t)BB * DD * 2;
  float* y2f = (float*)(ws + off);                     off += (size_t)NP * 4;
  float* x2f = (float*)(ws + off);                     off += 512 * 4;
  float* inv2s2f = (float*)(ws + off);                 off += 512 * 4;
  if (ws_size < off) return;

  zero_kernel<<<dim3(1536), dim3(256), 0, stream>>>((f32x4*)out);
  prep_x_kernel<<<dim3(512), dim3(256), 0, stream>>>(x, sigma, xhif, xlof, x2f, inv2s2f);
  y2_kernel<<<dim3(NREAL), dim3(256), 0, stream>>>(y, y2f);
  qk_fb_kernel<<<dim3(1568), dim3(256), 0, stream>>>(y, xhif, xlof, x2f, inv2s2f, y2f, Sf);
  softmax_kernel<<<dim3(512), dim3(256), 0, stream>>>(Sf, Pf);
  pv_fb_kernel<<<dim3(768), dim3(256), 0, stream>>>(y, Pf, out);
}